// Round 1
// 304.453 us; speedup vs baseline: 1.1993x; 1.1993x over previous
//
#include <hip/hip_runtime.h>
#include <stdint.h>

#define NF 8192
#define NX 2048
#define MROWS 8192
#define NGROUPS 32
#define NTILE 32   // NX/64 K-tiles

typedef unsigned short u16;
typedef __bf16 bf16x8 __attribute__((ext_vector_type(8)));
typedef float f32x4 __attribute__((ext_vector_type(4)));

#define AS1 __attribute__((address_space(1)))
#define AS3 __attribute__((address_space(3)))

// async global->LDS, 16B/lane; LDS dest = wave-uniform base + lane*16.
__device__ __forceinline__ void glds16(const void* g, void* l) {
    __builtin_amdgcn_global_load_lds((AS1 void*)(uintptr_t)g,
                                     (AS3 void*)(uintptr_t)l, 16, 0, 0);
}

__device__ __forceinline__ u16 f2bf(float f) {
    unsigned u = __float_as_uint(f);
    return (u16)((u + 0x7FFFu + ((u >> 16) & 1u)) >> 16);  // RNE
}

// packed [NF, NX/2] (one byte per int32, two nibbles) -> W bf16 [NF, NX] row-major.
__global__ void dequant_kernel(const int* __restrict__ packed,
                               const float* __restrict__ scales,
                               const int* __restrict__ zeros,
                               uint32_t* __restrict__ W2) {
    int tid = blockIdx.x * blockDim.x + threadIdx.x;   // [0, NF*NX/2)
    int f = tid >> 10;          // NX/2 = 1024 per row
    int i = tid & 1023;
    int g = f * NGROUPS + (i >> 5);
    int p = packed[tid];
    float s = scales[g];
    float z = (float)zeros[g];
    float w0 = ((float)(p & 15) - z) * s;
    float w1 = ((float)((p >> 4) & 15) - z) * s;
    W2[tid] = (uint32_t)f2bf(w0) | ((uint32_t)f2bf(w1) << 16);
}

// x fp32 -> bf16, 4 elems/thread
__global__ void cvt_kernel(const float4* __restrict__ x, ushort4* __restrict__ y) {
    int i = blockIdx.x * blockDim.x + threadIdx.x;
    float4 v = x[i];
    ushort4 o;
    o.x = f2bf(v.x); o.y = f2bf(v.y); o.z = f2bf(v.z); o.w = f2bf(v.w);
    y[i] = o;
}

// ===========================================================================
// 256x256 tile, BK=64, 8 waves (2Mx4N), 8-phase (4/phase-per-K-tile) schedule
// with counted vmcnt (T3+T4), st-swizzled LDS (T2, via inverse-swizzled
// global source + swizzled ds_read — global_load_lds writes linearly),
// setprio around MFMA clusters (T5), bijective XCD blockIdx swizzle (T1).
//
// LDS per buffer (64 KiB), 2 buffers = 128 KiB:
//   +0      A1: A rows m0-3 of both wave-halves  ({0-63}->blk rows 0-63,
//                                                 {64-127}->blk rows 128-191)
//   +16384  A2: A rows m4-7                      (blk rows 64-127 / 192-255)
//   +32768  B2: B rows n0-1 per wn               (ldsrow wn*32+r -> blk wn*64+r)
//   +49152  B1: B rows n2-3 per wn               (-> blk wn*64+32+r)
// Each unit = 16 KiB = 128 lds-rows of 128 B = 2 x glds16 per thread.
//
// Swizzle: 16B slot within a 128B row: phys_slot = logical_slot ^ (row & 7).
// Write side: linear LDS dest, source col-slot = (t&7) ^ ((t>>3)&7).
// Read side:  byte = row*128 + ((kk*4+quad) ^ (l15&7))*16.  (involution both sides)
//
// Per K-tile (4 phases), quadrant order (mh,np) = (0,0),(0,1),(1,1),(1,0):
//   ph1: read a[m0-3] (8) + b[n0-1] (4); stage B2(T+1)->buf^1 ; MFMA acc[0-3][0-1]
//   ph2: read b[n2-3] (4)             ; stage A1(T+2)->buf    ; MFMA acc[0-3][2-3]
//   ph3: read a[m4-7] (8)             ; stage B1(T+2)->buf    ; MFMA acc[4-7][2-3]
//   ph4: read b[n0-1] (4)             ; stage A2(T+2)->buf    ; MFMA acc[4-7][0-1]
//        then vmcnt(6) (last 3 units in flight) + barrier.
// Staged region at phase p was last ds_read at phase p-1 (ordered by its
// lgkmcnt(0) + end barrier).  vmcnt(6) at each ph4 completes exactly the next
// tile's 4 units.  Tail (T >= NTILE-2): vmcnt(0).
// ===========================================================================

#define MFMA16(d, va, vb) d = __builtin_amdgcn_mfma_f32_16x16x32_bf16(va, vb, d, 0, 0, 0)

#define PH_PRE() \
    __builtin_amdgcn_sched_barrier(0); \
    __builtin_amdgcn_s_barrier(); \
    asm volatile("s_waitcnt lgkmcnt(0)" ::: "memory"); \
    __builtin_amdgcn_sched_barrier(0)

#define PH_POST() \
    __builtin_amdgcn_sched_barrier(0); \
    __builtin_amdgcn_s_barrier()

#define STAGE(unitOff, bufOff, s0, s1, koff) do { \
    glds16((s0) + (koff), dst0 + (unitOff) + (bufOff)); \
    glds16((s1) + (koff), dst1 + (unitOff) + (bufOff)); \
} while (0)

__global__ __launch_bounds__(512, 2)
void gemm_kernel(const u16* __restrict__ A, const u16* __restrict__ B,
                 const float* __restrict__ bias, float* __restrict__ C) {
    __shared__ __align__(16) char smem[131072];

    const int t = threadIdx.x;

    // T1: bijective XCD swizzle (1024 blocks % 8 == 0): each XCD gets a
    // contiguous chunk = 4 M-rows of the 32x32 block grid; consecutive
    // dispatches within an XCD walk N with fixed A-panel (L2 reuse).
    const int bid = blockIdx.x;
    const int swz = (bid & 7) * 128 + (bid >> 3);
    const int by = swz >> 5;
    const int bx = swz & 31;
    const int rowA0 = by * 256;
    const int rowB0 = bx * 256;

    // ---- staging addressing (inverse-swizzled global source) ----
    const int tr = t >> 3;                 // lds-row within unit for load 0
    const int slot = (t & 7) ^ (tr & 7);   // source 16B-slot (involution)
    const int s16 = slot * 16;

    const char* Ab = (const char*)A;       // row stride NX*2 = 4096 B
    const char* Bb = (const char*)B;
    const char* srcA1_0 = Ab + (size_t)(rowA0 + tr)       * 4096 + s16;
    const char* srcA1_1 = Ab + (size_t)(rowA0 + 128 + tr) * 4096 + s16;
    const char* srcA2_0 = Ab + (size_t)(rowA0 + 64 + tr)  * 4096 + s16;
    const char* srcA2_1 = Ab + (size_t)(rowA0 + 192 + tr) * 4096 + s16;
    const int rb = (tr >> 5) * 64 + (tr & 31);
    const char* srcB2_0 = Bb + (size_t)(rowB0 + rb)       * 4096 + s16;
    const char* srcB2_1 = Bb + (size_t)(rowB0 + 128 + rb) * 4096 + s16;
    const char* srcB1_0 = Bb + (size_t)(rowB0 + 32 + rb)  * 4096 + s16;
    const char* srcB1_1 = Bb + (size_t)(rowB0 + 160 + rb) * 4096 + s16;

    char* dst0 = smem + t * 16;            // linear LDS dest (glds requirement)
    char* dst1 = smem + (t + 512) * 16;

    // ---- fragment read addressing (swizzled) ----
    const int lane = t & 63;
    const int wv = t >> 6;
    const int wm = wv >> 2;                // 0..1  (M half, 128 rows)
    const int wn = wv & 3;                 // 0..3  (N quarter, 64 cols)
    const int l15 = lane & 15;
    const int quad = lane >> 4;            // 0..3
    const int l7 = l15 & 7;
    const int sx0 = (quad ^ l7) << 4;        // kk=0 slot, swizzled
    const int sx1 = ((4 + quad) ^ l7) << 4;  // kk=1 slot, swizzled
    const int aRd = (wm * 64 + l15) * 128;           // + (i>>2)*16384 + (i&3)*2048
    const int bRd = 32768 + (wn * 32 + l15) * 128;   // + (n>>1)*16384 + (n&1)*2048

    f32x4 acc[8][4];
#pragma unroll
    for (int i = 0; i < 8; ++i)
#pragma unroll
        for (int n = 0; n < 4; ++n) acc[i][n] = {0.f, 0.f, 0.f, 0.f};

    bf16x8 a[4][2], b[2][2];

    // ---- prologue: tile0 all 4 units, tile1 {A1,B1,A2}; vmcnt(6) completes
    // tile0 (oldest 8 loads), leaving tile1's 3 units in flight = steady state.
    STAGE(0,     0,     srcA1_0, srcA1_1, 0);
    STAGE(16384, 0,     srcA2_0, srcA2_1, 0);
    STAGE(32768, 0,     srcB2_0, srcB2_1, 0);
    STAGE(49152, 0,     srcB1_0, srcB1_1, 0);
    STAGE(0,     65536, srcA1_0, srcA1_1, 128);
    STAGE(49152, 65536, srcB1_0, srcB1_1, 128);
    STAGE(16384, 65536, srcA2_0, srcA2_1, 128);
    asm volatile("s_waitcnt vmcnt(6)" ::: "memory");
    __builtin_amdgcn_s_barrier();

    int kB2 = 128;   // byte K-offset of B2 stage target (tile T+1)
    int kOth = 256;  // byte K-offset of A1/B1/A2 stage targets (tile T+2)

#pragma unroll 1
    for (int T = 0; T < NTILE; ++T) {
        const int bo = (T & 1) << 16;   // buffer being consumed
        const int so = bo ^ 65536;      // buffer receiving B2(T+1)

        // ---------- phase 1: quadrant (m0-3, n0-1) ----------
#pragma unroll
        for (int i = 0; i < 4; ++i) {
            a[i][0] = *(const bf16x8*)(smem + bo + aRd + i * 2048 + sx0);
            a[i][1] = *(const bf16x8*)(smem + bo + aRd + i * 2048 + sx1);
        }
#pragma unroll
        for (int n = 0; n < 2; ++n) {
            b[n][0] = *(const bf16x8*)(smem + bo + bRd + n * 2048 + sx0);
            b[n][1] = *(const bf16x8*)(smem + bo + bRd + n * 2048 + sx1);
        }
        if (T + 1 < NTILE) STAGE(32768, so, srcB2_0, srcB2_1, kB2);
        PH_PRE();
        __builtin_amdgcn_s_setprio(1);
#pragma unroll
        for (int i = 0; i < 4; ++i)
#pragma unroll
            for (int n = 0; n < 2; ++n) {
                MFMA16(acc[i][n], a[i][0], b[n][0]);
                MFMA16(acc[i][n], a[i][1], b[n][1]);
            }
        __builtin_amdgcn_s_setprio(0);
        PH_POST();

        // ---------- phase 2: quadrant (m0-3, n2-3) ----------
#pragma unroll
        for (int n = 0; n < 2; ++n) {
            b[n][0] = *(const bf16x8*)(smem + bo + bRd + 16384 + n * 2048 + sx0);
            b[n][1] = *(const bf16x8*)(smem + bo + bRd + 16384 + n * 2048 + sx1);
        }
        if (T + 2 < NTILE) STAGE(0, bo, srcA1_0, srcA1_1, kOth);
        PH_PRE();
        __builtin_amdgcn_s_setprio(1);
#pragma unroll
        for (int i = 0; i < 4; ++i)
#pragma unroll
            for (int n = 0; n < 2; ++n) {
                MFMA16(acc[i][2 + n], a[i][0], b[n][0]);
                MFMA16(acc[i][2 + n], a[i][1], b[n][1]);
            }
        __builtin_amdgcn_s_setprio(0);
        PH_POST();

        // ---------- phase 3: quadrant (m4-7, n2-3) ----------
#pragma unroll
        for (int i = 0; i < 4; ++i) {
            a[i][0] = *(const bf16x8*)(smem + bo + 16384 + aRd + i * 2048 + sx0);
            a[i][1] = *(const bf16x8*)(smem + bo + 16384 + aRd + i * 2048 + sx1);
        }
        if (T + 2 < NTILE) STAGE(49152, bo, srcB1_0, srcB1_1, kOth);
        PH_PRE();
        __builtin_amdgcn_s_setprio(1);
#pragma unroll
        for (int i = 0; i < 4; ++i)
#pragma unroll
            for (int n = 0; n < 2; ++n) {
                MFMA16(acc[4 + i][2 + n], a[i][0], b[n][0]);
                MFMA16(acc[4 + i][2 + n], a[i][1], b[n][1]);
            }
        __builtin_amdgcn_s_setprio(0);
        PH_POST();

        // ---------- phase 4: quadrant (m4-7, n0-1) ----------
#pragma unroll
        for (int n = 0; n < 2; ++n) {
            b[n][0] = *(const bf16x8*)(smem + bo + bRd + n * 2048 + sx0);
            b[n][1] = *(const bf16x8*)(smem + bo + bRd + n * 2048 + sx1);
        }
        if (T + 2 < NTILE) STAGE(16384, bo, srcA2_0, srcA2_1, kOth);
        PH_PRE();
        __builtin_amdgcn_s_setprio(1);
#pragma unroll
        for (int i = 0; i < 4; ++i)
#pragma unroll
            for (int n = 0; n < 2; ++n) {
                MFMA16(acc[4 + i][n], a[i][0], b[n][0]);
                MFMA16(acc[4 + i][n], a[i][1], b[n][1]);
            }
        __builtin_amdgcn_s_setprio(0);
        __builtin_amdgcn_sched_barrier(0);
        if (T < NTILE - 2) asm volatile("s_waitcnt vmcnt(6)" ::: "memory");
        else               asm volatile("s_waitcnt vmcnt(0)" ::: "memory");
        __builtin_amdgcn_sched_barrier(0);
        __builtin_amdgcn_s_barrier();

        kB2 += 128; kOth += 128;
    }

    // ---- epilogue: C/D layout col = l15, row = quad*4 + reg ----
    const int col0 = rowB0 + wn * 64 + l15;
    const int row0 = rowA0 + wm * 128 + quad * 4;
    float bj[4];
#pragma unroll
    for (int n = 0; n < 4; ++n) bj[n] = bias[col0 + n * 16];
#pragma unroll
    for (int i = 0; i < 8; ++i) {
#pragma unroll
        for (int r = 0; r < 4; ++r) {
            float* crow = C + (size_t)(row0 + i * 16 + r) * NF;
#pragma unroll
            for (int n = 0; n < 4; ++n)
                crow[col0 + n * 16] = acc[i][n][r] + bj[n];
        }
    }
}

extern "C" void kernel_launch(void* const* d_in, const int* in_sizes, int n_in,
                              void* d_out, int out_size, void* d_ws, size_t ws_size,
                              hipStream_t stream) {
    const float* x      = (const float*)d_in[0];   // [4,2048,2048] fp32
    const int* packed   = (const int*)d_in[1];     // [8192,1024]
    const float* scales = (const float*)d_in[2];   // [8192,32]
    const int* zeros    = (const int*)d_in[3];     // [8192,32]
    const float* bias   = (const float*)d_in[4];   // [8192]
    float* out = (float*)d_out;                    // [8192, 8192] fp32

    // workspace: W bf16 (32 MiB) + x bf16 (32 MiB); fully rewritten every call
    u16* Wq = (u16*)d_ws;
    u16* Xb = Wq + (size_t)NF * NX;

    dequant_kernel<<<(NF * (NX / 2)) / 256, 256, 0, stream>>>(packed, scales, zeros, (uint32_t*)Wq);
    cvt_kernel<<<(MROWS * NX / 4) / 256, 256, 0, stream>>>((const float4*)x, (ushort4*)Xb);

    gemm_kernel<<<dim3((MROWS / 256) * (NF / 256)), 512, 0, stream>>>(Xb, Wq, bias, out);
}